// Round 8
// baseline (806.322 us; speedup 1.0000x reference)
//
#include <hip/hip_runtime.h>
#include <math.h>

#define EPS 1e-8f

typedef float vfloat4 __attribute__((ext_vector_type(4)));
typedef float vfloat2 __attribute__((ext_vector_type(2)));

// ---------------- prep kernel (fused transpose + Gram) ----------------
__global__ void prep_all(const float* __restrict__ W_enc,
                         const float* __restrict__ Wd, const float* __restrict__ bd,
                         float* __restrict__ wt, float* __restrict__ G,
                         float* __restrict__ h, float* __restrict__ bb) {
    int b = blockIdx.x;
    int lane = threadIdx.x;     // 64
    if (b < 384) {
        int i = b * 64 + lane;  // 0..24575
        int k = i / 24, l = i - k * 24;
        wt[i] = W_enc[l * 1024 + k];
        return;
    }
    b -= 384;
    float s = 0.f;
    if (b < 576) {
        int l = b / 24, m = b - (b / 24) * 24;
        for (int d = lane; d < 1024; d += 64) s = fmaf(Wd[d * 24 + l], Wd[d * 24 + m], s);
    } else if (b < 600) {
        int l = b - 576;
        for (int d = lane; d < 1024; d += 64) s = fmaf(Wd[d * 24 + l], bd[d], s);
    } else {
        for (int d = lane; d < 1024; d += 64) s = fmaf(bd[d], bd[d], s);
    }
    for (int off = 32; off; off >>= 1) s += __shfl_down(s, off);
    if (lane == 0) {
        if (b < 576) G[b] = s;
        else if (b < 600) h[b - 576] = s;
        else *bb = s;
    }
}

// ---------------- main kernel ----------------
// r7 CHANGE: NO x LDS tile. Each lane loads ITS OWN two rows (r, r+64)
// directly from global into VGPRs (vfloat4[8] per row per chunk, full
// unroll -> static indexing, no scratch). Uncoalesced per-instruction
// (4 KB lane stride) but each lane covers contiguous 128 B/chunk -> full
// line utilization, HBM volume unchanged; TA cost ~3-5 us/CU replaces
// ~20 us/CU of LDS tile round-trip + removes the per-chunk staged-write
// serialization in the in-order DS pipe. Decode: accumulate in regs,
// store straight to out (contiguous 128 B/lane/chunk). Hot-loop DS ops
// are ONLY the 6 uniform weight ds_read_b128 per kk (counted lgkmcnt).
// LDS: 8x800 weight regions + 8x(25x64 float2) combine scratch = 125 KB.
// FMA order identical to r6 -> bit-identical output.

constexpr int BROWS  = 128;
constexpr int NW     = 8;
constexpr int WREG_F = 800;                 // 768 weights + 32 bias
constexpr int COMB_F = 25 * 64 * 2;         // per-wave combine (float2 x 25 x 64)
constexpr int SMEM_F = NW * WREG_F + NW * COMB_F;   // 6400+25600 = 32000 floats

__global__ __launch_bounds__(512, 2)
void leech_main(const float* __restrict__ data,
                const float* __restrict__ b_enc,
                const float* __restrict__ Wd,
                const float* __restrict__ b_dec,
                const float* __restrict__ ecs_p,
                const float* __restrict__ ep_p,
                const float* __restrict__ wt,
                const float* __restrict__ G,
                const float* __restrict__ h,
                const float* __restrict__ bbp,
                float* __restrict__ out)
{
    __shared__ float smem[SMEM_F];
    const int tid = threadIdx.x;
    const int w = tid >> 6;         // 0..7
    const int r = tid & 63;
    const int rowbase = blockIdx.x * BROWS;

    float* wreg = smem + w * WREG_F;                       // wave-private weights
    vfloat2* cw = (vfloat2*)(smem + NW * WREG_F) + w * 25 * 64;  // this wave's combine
    vfloat2* cb = (vfloat2*)(smem + NW * WREG_F);               // block combine base

    const int kw = __builtin_amdgcn_readfirstlane((tid >> 6) * 128);

    const size_t row0 = (size_t)(rowbase + r);
    const size_t row1 = row0 + 64;
    const float* pr0 = data + row0 * 1024 + kw;
    const float* pr1 = data + row1 * 1024 + kw;

    float proj0[24], proj1[24];
#pragma unroll
    for (int l = 0; l < 24; ++l) { proj0[l] = 0.f; proj1[l] = 0.f; }
    float ssq0 = 0.f, ssq1 = 0.f;

    vfloat4 xa0[8], xa1[8], xb0[8], xb1[8];
    vfloat4 ew0, ew1, ew2;

#define XLOAD(X0, X1, sc) { \
    _Pragma("unroll") \
    for (int g = 0; g < 8; ++g) { \
        X0[g] = *(const vfloat4*)(pr0 + (sc) * 32 + g * 4); \
        X1[g] = *(const vfloat4*)(pr1 + (sc) * 32 + g * 4); \
    } }

#define EWLOAD(sc) { \
    const float* gs_ = wt + (size_t)(kw + (sc) * 32) * 24 + r * 12; \
    ew0 = *(const vfloat4*)gs_; \
    ew1 = *(const vfloat4*)(gs_ + 4); \
    ew2 = *(const vfloat4*)(gs_ + 8); }

#define EWSTORE() { \
    float* d_ = wreg + r * 12; \
    *(vfloat4*)d_ = ew0; *(vfloat4*)(d_ + 4) = ew1; *(vfloat4*)(d_ + 8) = ew2; }

#define ENC_COMP(X0, X1) { \
    _Pragma("unroll") \
    for (int kk = 0; kk < 32; ++kk) { \
        const float a = X0[kk >> 2][kk & 3]; \
        const float b = X1[kk >> 2][kk & 3]; \
        ssq0 = fmaf(a, a, ssq0); \
        ssq1 = fmaf(b, b, ssq1); \
        const float* wr_ = wreg + kk * 24; \
        vfloat4 q[6]; \
        _Pragma("unroll") \
        for (int t = 0; t < 6; ++t) q[t] = *(const vfloat4*)(wr_ + t * 4); \
        _Pragma("unroll") \
        for (int l = 0; l < 24; ++l) { \
            const float wv = q[l >> 2][l & 3]; \
            proj0[l] = fmaf(wv, a, proj0[l]); \
            proj1[l] = fmaf(wv, b, proj1[l]); \
        } \
    } }

    // ---- encode: 4 chunks, depth-1 x-prefetch, wreg ping via in-order DS ----
    EWLOAD(0); XLOAD(xa0, xa1, 0); EWSTORE();
    XLOAD(xb0, xb1, 1); EWLOAD(1);
    ENC_COMP(xa0, xa1);             // chunk 0
    EWSTORE(); EWLOAD(2); XLOAD(xa0, xa1, 2);
    ENC_COMP(xb0, xb1);             // chunk 1
    EWSTORE(); EWLOAD(3); XLOAD(xb0, xb1, 3);
    ENC_COMP(xa0, xa1);             // chunk 2
    EWSTORE();
    ENC_COMP(xb0, xb1);             // chunk 3

    // -------- combine partials across the 8 waves --------
#pragma unroll
    for (int l = 0; l < 24; ++l) {
        vfloat2 v; v.x = proj0[l]; v.y = proj1[l];
        cw[l * 64 + r] = v;
    }
    {
        vfloat2 v; v.x = ssq0; v.y = ssq1;
        cw[24 * 64 + r] = v;
    }
    __syncthreads();

    float p0[24], p1[24];
#pragma unroll
    for (int l = 0; l < 24; ++l) {
        vfloat2 a0 = cb[(0 * 25 + l) * 64 + r] + cb[(1 * 25 + l) * 64 + r];
        vfloat2 a1 = cb[(2 * 25 + l) * 64 + r] + cb[(3 * 25 + l) * 64 + r];
        vfloat2 a2 = cb[(4 * 25 + l) * 64 + r] + cb[(5 * 25 + l) * 64 + r];
        vfloat2 a3 = cb[(6 * 25 + l) * 64 + r] + cb[(7 * 25 + l) * 64 + r];
        vfloat2 s = (a0 + a1) + (a2 + a3);
        p0[l] = s.x; p1[l] = s.y;
    }
    float ss0, ss1;
    {
        vfloat2 a0 = cb[(0 * 25 + 24) * 64 + r] + cb[(1 * 25 + 24) * 64 + r];
        vfloat2 a1 = cb[(2 * 25 + 24) * 64 + r] + cb[(3 * 25 + 24) * 64 + r];
        vfloat2 a2 = cb[(4 * 25 + 24) * 64 + r] + cb[(5 * 25 + 24) * 64 + r];
        vfloat2 a3 = cb[(6 * 25 + 24) * 64 + r] + cb[(7 * 25 + 24) * 64 + r];
        vfloat2 s = (a0 + a1) + (a2 + a3);
        ss0 = s.x; ss1 = s.y;
    }
    __syncthreads();   // combine reads done before decode reuses nothing, but keep order

    // -------- per-row epilogue (two rows per lane) --------
    const float ecs = ecs_p[0];
    const float ep  = ep_p[0];

    float c0[24], c1[24];
    float s2a, s2b;
    {
        const float in_e = sqrtf(ss0);
        float lp[24]; float oe = 0.f;
#pragma unroll
        for (int l = 0; l < 24; ++l) {
            const float pp = p0[l] + b_enc[l];
            const float q = rintf(pp / ecs) * ecs;   // half-even, matches np
            lp[l] = q;
            oe = fmaf(q, q, oe);
        }
        const float s1 = in_e / (sqrtf(oe) + EPS) * ep;
        float ie = 0.f;
#pragma unroll
        for (int l = 0; l < 24; ++l) {
            const float lat = lp[l] * s1;
            ie = fmaf(lat, lat, ie);
            c0[l] = (fabsf(lat) > ecs) ? lat : 0.f;
        }
        const float in_e2 = sqrtf(ie);
        float qacc = bbp[0];
#pragma unroll
        for (int l = 0; l < 24; ++l) {
            float s = 2.f * h[l];
#pragma unroll
            for (int m = 0; m < 24; ++m)
                s = fmaf(G[l * 24 + m], c0[m], s);
            qacc = fmaf(s, c0[l], qacc);
        }
        const float out_e2 = sqrtf(fmaxf(qacc, 0.f));
        s2a = in_e2 / (out_e2 + EPS) * ep;
    }
    {
        const float in_e = sqrtf(ss1);
        float lp[24]; float oe = 0.f;
#pragma unroll
        for (int l = 0; l < 24; ++l) {
            const float pp = p1[l] + b_enc[l];
            const float q = rintf(pp / ecs) * ecs;
            lp[l] = q;
            oe = fmaf(q, q, oe);
        }
        const float s1 = in_e / (sqrtf(oe) + EPS) * ep;
        float ie = 0.f;
#pragma unroll
        for (int l = 0; l < 24; ++l) {
            const float lat = lp[l] * s1;
            ie = fmaf(lat, lat, ie);
            c1[l] = (fabsf(lat) > ecs) ? lat : 0.f;
        }
        const float in_e2 = sqrtf(ie);
        float qacc = bbp[0];
#pragma unroll
        for (int l = 0; l < 24; ++l) {
            float s = 2.f * h[l];
#pragma unroll
            for (int m = 0; m < 24; ++m)
                s = fmaf(G[l * 24 + m], c1[m], s);
            qacc = fmaf(s, c1[l], qacc);
        }
        const float out_e2 = sqrtf(fmaxf(qacc, 0.f));
        s2b = in_e2 / (out_e2 + EPS) * ep;
    }

    // -------- decode: registers -> direct per-lane-row stores, no tile -----
    float* po0 = out + row0 * 1024 + kw;
    float* po1 = out + row1 * 1024 + kw;
    vfloat4 bld;   // bias chunk (lanes r<8 stage it)

#define DWLOAD(sc) { \
    const float* gs_ = Wd + (size_t)(kw + (sc) * 32) * 24 + r * 12; \
    ew0 = *(const vfloat4*)gs_; \
    ew1 = *(const vfloat4*)(gs_ + 4); \
    ew2 = *(const vfloat4*)(gs_ + 8); \
    if (r < 8) bld = *(const vfloat4*)(b_dec + kw + (sc) * 32 + r * 4); }

#define DWSTORE() { \
    float* d_ = wreg + r * 12; \
    *(vfloat4*)d_ = ew0; *(vfloat4*)(d_ + 4) = ew1; *(vfloat4*)(d_ + 8) = ew2; \
    if (r < 8) *(vfloat4*)(wreg + 768 + r * 4) = bld; }

#define DEC_COMP(sc) { \
    _Pragma("unroll") \
    for (int q8 = 0; q8 < 8; ++q8) { \
        vfloat4 res0, res1; \
        _Pragma("unroll") \
        for (int i = 0; i < 4; ++i) { \
            const int dd = q8 * 4 + i; \
            const float* wr_ = wreg + dd * 24; \
            vfloat4 q[6]; \
            _Pragma("unroll") \
            for (int t = 0; t < 6; ++t) q[t] = *(const vfloat4*)(wr_ + t * 4); \
            const float bv = wreg[768 + dd]; \
            float acc0 = bv, acc1 = bv; \
            _Pragma("unroll") \
            for (int l = 0; l < 24; ++l) { \
                const float wv = q[l >> 2][l & 3]; \
                acc0 = fmaf(wv, c0[l], acc0); \
                acc1 = fmaf(wv, c1[l], acc1); \
            } \
            res0[i] = acc0 * s2a; \
            res1[i] = acc1 * s2b; \
        } \
        __builtin_nontemporal_store(res0, (vfloat4*)(po0 + (sc) * 32 + q8 * 4)); \
        __builtin_nontemporal_store(res1, (vfloat4*)(po1 + (sc) * 32 + q8 * 4)); \
    } }

    DWLOAD(0); DWSTORE();
    DWLOAD(1);
    DEC_COMP(0);
    DWSTORE(); DWLOAD(2);
    DEC_COMP(1);
    DWSTORE(); DWLOAD(3);
    DEC_COMP(2);
    DWSTORE();
    DEC_COMP(3);

#undef XLOAD
#undef EWLOAD
#undef EWSTORE
#undef ENC_COMP
#undef DWLOAD
#undef DWSTORE
#undef DEC_COMP
}

// ---------------- launcher ----------------

extern "C" void kernel_launch(void* const* d_in, const int* in_sizes, int n_in,
                              void* d_out, int out_size, void* d_ws, size_t ws_size,
                              hipStream_t stream) {
    const float* data  = (const float*)d_in[0];
    const float* W_enc = (const float*)d_in[1];
    const float* b_enc = (const float*)d_in[2];
    const float* W_dec = (const float*)d_in[3];
    const float* b_dec = (const float*)d_in[4];
    const float* ecs   = (const float*)d_in[5];
    const float* ep    = (const float*)d_in[6];
    float* out = (float*)d_out;

    float* ws = (float*)d_ws;
    float* wt = ws;                 // 24576 floats: W_enc transposed, k-major
    float* G  = ws + 24576;         // 576
    float* h  = ws + 25152;         // 24
    float* bb = ws + 25176;         // 1

    const int rows = in_sizes[0] / 1024;    // 32768

    hipLaunchKernelGGL(prep_all, dim3(985), dim3(64), 0, stream,
                       W_enc, W_dec, b_dec, wt, G, h, bb);
    hipLaunchKernelGGL(leech_main, dim3(rows / BROWS), dim3(512), 0, stream,
                       data, b_enc, W_dec, b_dec, ecs, ep, wt, G, h, bb, out);
}

// Round 9
// 409.272 us; speedup vs baseline: 1.9701x; 1.9701x over previous
//
#include <hip/hip_runtime.h>
#include <math.h>

#define EPS 1e-8f

typedef float vfloat4 __attribute__((ext_vector_type(4)));
typedef float vfloat2 __attribute__((ext_vector_type(2)));

// ---------------- prep kernel (fused transpose + Gram) ----------------
__global__ void prep_all(const float* __restrict__ W_enc,
                         const float* __restrict__ Wd, const float* __restrict__ bd,
                         float* __restrict__ wt, float* __restrict__ G,
                         float* __restrict__ h, float* __restrict__ bb) {
    int b = blockIdx.x;
    int lane = threadIdx.x;     // 64
    if (b < 384) {
        int i = b * 64 + lane;  // 0..24575
        int k = i / 24, l = i - k * 24;
        wt[i] = W_enc[l * 1024 + k];
        return;
    }
    b -= 384;
    float s = 0.f;
    if (b < 576) {
        int l = b / 24, m = b - (b / 24) * 24;
        for (int d = lane; d < 1024; d += 64) s = fmaf(Wd[d * 24 + l], Wd[d * 24 + m], s);
    } else if (b < 600) {
        int l = b - 576;
        for (int d = lane; d < 1024; d += 64) s = fmaf(Wd[d * 24 + l], bd[d], s);
    } else {
        for (int d = lane; d < 1024; d += 64) s = fmaf(bd[d], bd[d], s);
    }
    for (int off = 32; off; off >>= 1) s += __shfl_down(s, off);
    if (lane == 0) {
        if (b < 576) G[b] = s;
        else if (b < 600) h[b - 576] = s;
        else *bb = s;
    }
}

// ---------------- main kernel ----------------
// r8: coalesced LDS transpose tile RESTORED (r7's direct global access caused
// 4x write amplification: 16B/lane nt stores at 4KB stride). New vs r6:
// 1) Hot loops have ZERO DS ops: weights come via s_load (SGPR operand
//    broadcast is the only zero-bandwidth fan-out; r6's uniform ds_read_b128
//    still pays the 1KB/wave return-crossbar floor ~12cyc -> 123us = r6's
//    measured wall). x is pre-read per chunk from tile into VGPRs, so the
//    loop never mixes ds_read with s_load in lgkmcnt (r4's failure mode).
// 2) Tile stride TW=36 floats (16B aligned): all staging/reads are b128
//    (4x fewer DS instrs than r6's scalar swizzle), bandwidth-floor clean.
// Block = 512 thr (8 waves); 128 rows/block; grid 256 = 1 block/CU.
// Lane r owns rows r and r+64. FMA order identical -> bit-identical output.

constexpr int BROWS  = 128;
constexpr int TW     = 36;                 // padded row stride (floats)
constexpr int TILE_F = BROWS * TW;         // 4608 floats per wave
constexpr int NW     = 8;
constexpr int SMEM_F = NW * TILE_F;        // 36864 floats = 144 KiB

__global__ __launch_bounds__(512, 2)
void leech_main(const float* __restrict__ data,
                const float* __restrict__ b_enc,
                const float* __restrict__ Wd,
                const float* __restrict__ b_dec,
                const float* __restrict__ ecs_p,
                const float* __restrict__ ep_p,
                const float* __restrict__ wt,
                const float* __restrict__ G,
                const float* __restrict__ h,
                const float* __restrict__ bbp,
                float* __restrict__ out)
{
    __shared__ float smem[SMEM_F];
    const int tid = threadIdx.x;
    const int w = tid >> 6;         // 0..7
    const int r = tid & 63;
    const int rowbase = blockIdx.x * BROWS;

    float* tile = smem + w * TILE_F;
    const int lrow = r >> 3;        // 0..7
    const int lk   = (r & 7) * 4;   // 0,4,...,28
    const int kw = __builtin_amdgcn_readfirstlane((tid >> 6) * 128);

    // -------- encode --------
    float proj0[24], proj1[24];
#pragma unroll
    for (int l = 0; l < 24; ++l) { proj0[l] = 0.f; proj1[l] = 0.f; }
    float ssq0 = 0.f, ssq1 = 0.f;

    vfloat4 buf[16];
#pragma unroll
    for (int it = 0; it < 16; ++it)
        buf[it] = *(const vfloat4*)(data + (size_t)(rowbase + it * 8 + lrow) * 1024 + kw + lk);

    for (int sc = 0; sc < 4; ++sc) {
        // stage current chunk (b128, wave-private; same-wave DS in-order)
#pragma unroll
        for (int it = 0; it < 16; ++it)
            *(vfloat4*)(tile + (it * 8 + lrow) * TW + lk) = buf[it];
        // prefetch next chunk's global loads (in flight through compute)
        if (sc < 3) {
            const int k0n = kw + (sc + 1) * 32;
#pragma unroll
            for (int it = 0; it < 16; ++it)
                buf[it] = *(const vfloat4*)(data + (size_t)(rowbase + it * 8 + lrow) * 1024 + k0n + lk);
        }
        // pull own two rows into registers (b128; only DS ops this chunk)
        vfloat4 xr0[8], xr1[8];
#pragma unroll
        for (int g = 0; g < 8; ++g) {
            xr0[g] = *(const vfloat4*)(tile + r * TW + g * 4);
            xr1[g] = *(const vfloat4*)(tile + (r + 64) * TW + g * 4);
        }
        // pure s_load + VALU loop (no DS): weights broadcast via SGPRs
        const int kofs = __builtin_amdgcn_readfirstlane(kw + sc * 32);
        const float* wp0 = wt + (size_t)kofs * 24;
#pragma unroll
        for (int kk = 0; kk < 32; ++kk) {
            const float a = xr0[kk >> 2][kk & 3];
            const float b = xr1[kk >> 2][kk & 3];
            ssq0 = fmaf(a, a, ssq0);
            ssq1 = fmaf(b, b, ssq1);
            const float* wp = wp0 + kk * 24;     // uniform -> s_load_dwordx8
#pragma unroll
            for (int l = 0; l < 24; ++l) {
                const float wv = wp[l];
                proj0[l] = fmaf(wv, a, proj0[l]);
                proj1[l] = fmaf(wv, b, proj1[l]);
            }
        }
    }

    // -------- combine partials across the 8 waves (overlay own tile) -------
    {
        vfloat2* cw = (vfloat2*)tile;
#pragma unroll
        for (int l = 0; l < 24; ++l) {
            vfloat2 v; v.x = proj0[l]; v.y = proj1[l];
            cw[l * 64 + r] = v;
        }
        vfloat2 v; v.x = ssq0; v.y = ssq1;
        cw[24 * 64 + r] = v;
    }
    __syncthreads();

#define CB(wv, i) (((const vfloat2*)(smem + (wv) * TILE_F))[(i) * 64 + r])
    float p0[24], p1[24];
#pragma unroll
    for (int l = 0; l < 24; ++l) {
        vfloat2 a0 = CB(0, l) + CB(1, l);
        vfloat2 a1 = CB(2, l) + CB(3, l);
        vfloat2 a2 = CB(4, l) + CB(5, l);
        vfloat2 a3 = CB(6, l) + CB(7, l);
        vfloat2 s = (a0 + a1) + (a2 + a3);
        p0[l] = s.x; p1[l] = s.y;
    }
    float ss0, ss1;
    {
        vfloat2 a0 = CB(0, 24) + CB(1, 24);
        vfloat2 a1 = CB(2, 24) + CB(3, 24);
        vfloat2 a2 = CB(4, 24) + CB(5, 24);
        vfloat2 a3 = CB(6, 24) + CB(7, 24);
        vfloat2 s = (a0 + a1) + (a2 + a3);
        ss0 = s.x; ss1 = s.y;
    }
#undef CB
    __syncthreads();   // all combine reads done before decode overwrites tiles

    // -------- per-row epilogue (two rows per lane) --------
    const float ecs = ecs_p[0];
    const float ep  = ep_p[0];

    float c0[24], c1[24];
    float s2a, s2b;
    {
        const float in_e = sqrtf(ss0);
        float lp[24]; float oe = 0.f;
#pragma unroll
        for (int l = 0; l < 24; ++l) {
            const float pp = p0[l] + b_enc[l];
            const float q = rintf(pp / ecs) * ecs;   // half-even, matches np
            lp[l] = q;
            oe = fmaf(q, q, oe);
        }
        const float s1 = in_e / (sqrtf(oe) + EPS) * ep;
        float ie = 0.f;
#pragma unroll
        for (int l = 0; l < 24; ++l) {
            const float lat = lp[l] * s1;
            ie = fmaf(lat, lat, ie);
            c0[l] = (fabsf(lat) > ecs) ? lat : 0.f;
        }
        const float in_e2 = sqrtf(ie);
        float qacc = bbp[0];
#pragma unroll
        for (int l = 0; l < 24; ++l) {
            float s = 2.f * h[l];
#pragma unroll
            for (int m = 0; m < 24; ++m)
                s = fmaf(G[l * 24 + m], c0[m], s);
            qacc = fmaf(s, c0[l], qacc);
        }
        const float out_e2 = sqrtf(fmaxf(qacc, 0.f));
        s2a = in_e2 / (out_e2 + EPS) * ep;
    }
    {
        const float in_e = sqrtf(ss1);
        float lp[24]; float oe = 0.f;
#pragma unroll
        for (int l = 0; l < 24; ++l) {
            const float pp = p1[l] + b_enc[l];
            const float q = rintf(pp / ecs) * ecs;
            lp[l] = q;
            oe = fmaf(q, q, oe);
        }
        const float s1 = in_e / (sqrtf(oe) + EPS) * ep;
        float ie = 0.f;
#pragma unroll
        for (int l = 0; l < 24; ++l) {
            const float lat = lp[l] * s1;
            ie = fmaf(lat, lat, ie);
            c1[l] = (fabsf(lat) > ecs) ? lat : 0.f;
        }
        const float in_e2 = sqrtf(ie);
        float qacc = bbp[0];
#pragma unroll
        for (int l = 0; l < 24; ++l) {
            float s = 2.f * h[l];
#pragma unroll
            for (int m = 0; m < 24; ++m)
                s = fmaf(G[l * 24 + m], c1[m], s);
            qacc = fmaf(s, c1[l], qacc);
        }
        const float out_e2 = sqrtf(fmaxf(qacc, 0.f));
        s2b = in_e2 / (out_e2 + EPS) * ep;
    }

    // -------- decode: regs -> tile (b128) -> coalesced nt stores ----------
    for (int sc = 0; sc < 4; ++sc) {
        const int dofs = __builtin_amdgcn_readfirstlane(kw + sc * 32);
        const float* wq0 = Wd + (size_t)dofs * 24;
        const float* bq  = b_dec + dofs;
        vfloat4 res0[8], res1[8];
#pragma unroll
        for (int dd = 0; dd < 32; ++dd) {
            const float* wp = wq0 + dd * 24;     // uniform -> s_load
            const float bv = bq[dd];
            float acc0 = bv, acc1 = bv;
#pragma unroll
            for (int l = 0; l < 24; ++l) {
                const float wv = wp[l];
                acc0 = fmaf(wv, c0[l], acc0);
                acc1 = fmaf(wv, c1[l], acc1);
            }
            res0[dd >> 2][dd & 3] = acc0 * s2a;
            res1[dd >> 2][dd & 3] = acc1 * s2b;
        }
        // own rows -> tile (b128; same-wave in-order)
#pragma unroll
        for (int g = 0; g < 8; ++g) {
            *(vfloat4*)(tile + r * TW + g * 4) = res0[g];
            *(vfloat4*)(tile + (r + 64) * TW + g * 4) = res1[g];
        }
        // coalesced read-out + full-line nt stores
#pragma unroll
        for (int it = 0; it < 16; ++it) {
            vfloat4 v = *(const vfloat4*)(tile + (it * 8 + lrow) * TW + lk);
            __builtin_nontemporal_store(v, (vfloat4*)(
                out + (size_t)(rowbase + it * 8 + lrow) * 1024 + dofs + lk));
        }
    }
}

// ---------------- launcher ----------------

extern "C" void kernel_launch(void* const* d_in, const int* in_sizes, int n_in,
                              void* d_out, int out_size, void* d_ws, size_t ws_size,
                              hipStream_t stream) {
    const float* data  = (const float*)d_in[0];
    const float* W_enc = (const float*)d_in[1];
    const float* b_enc = (const float*)d_in[2];
    const float* W_dec = (const float*)d_in[3];
    const float* b_dec = (const float*)d_in[4];
    const float* ecs   = (const float*)d_in[5];
    const float* ep    = (const float*)d_in[6];
    float* out = (float*)d_out;

    float* ws = (float*)d_ws;
    float* wt = ws;                 // 24576 floats: W_enc transposed, k-major
    float* G  = ws + 24576;         // 576
    float* h  = ws + 25152;         // 24
    float* bb = ws + 25176;         // 1

    const int rows = in_sizes[0] / 1024;    // 32768

    hipLaunchKernelGGL(prep_all, dim3(985), dim3(64), 0, stream,
                       W_enc, W_dec, b_dec, wt, G, h, bb);
    hipLaunchKernelGGL(leech_main, dim3(rows / BROWS), dim3(512), 0, stream,
                       data, b_enc, W_dec, b_dec, ecs, ep, wt, G, h, bb, out);
}